// Round 10
// baseline (445.885 us; speedup 1.0000x reference)
//
#include <hip/hip_runtime.h>

// Swin shifted-window attention, MI355X gfx950.  R9 = R7 base (best, 377us) +
// f16-preconverted, PRE-SWIZZLED weights in __device__ globals + B staged via
// global_load_lds (BK=64 dbuf, 1 plain __syncthreads per 2 K-steps, no asm waits,
// no VALU staging in the K-loop).
// k_wcvt -> k_qkv (A-in-reg, B gload_lds) -> k_attn -> k_out (same).
// d_out holds q|k f16 overlay until k_out overwrites it (fp32).
// ws: [0,64MiB) ao; [64,128MiB) vt.

using f16   = _Float16;
using f16x8 = __attribute__((ext_vector_type(8))) _Float16;
using f16x4 = __attribute__((ext_vector_type(4))) _Float16;
using f32x4 = __attribute__((ext_vector_type(4))) float;

#define MFMA16(a, b, c) __builtin_amdgcn_mfma_f32_16x16x32_f16((a), (b), (c), 0, 0, 0)
#define SCHEDBAR() __builtin_amdgcn_sched_barrier(0)
#define LGKM0()  asm volatile("s_waitcnt lgkmcnt(0)" ::: "memory")

static constexpr int QK_HALF = 65536 * 512;

// f16 weights, pre-swizzled: [n*512 + kb*64 + s*8 + e] = w[n][kb*64 + (s^(n&7))*8 + e]
__device__ f16 g_wq16[1536 * 512];
__device__ f16 g_wo16[512 * 512];

typedef const __attribute__((address_space(1))) unsigned int* gp_t;
typedef __attribute__((address_space(3))) unsigned int* sp_t;
__device__ __forceinline__ void gl_lds16(const f16* g, f16* s) {
  __builtin_amdgcn_global_load_lds((gp_t)g, (sp_t)s, 16, 0, 0);
}

__device__ __forceinline__ void nts4f(f32x4 v, float* p) {
  __builtin_nontemporal_store(v, (f32x4*)p);
}

__device__ __forceinline__ int tok2patch(int t) {
  int b = t >> 12, rem = t & 4095;
  int widx = rem >> 6, s = rem & 63;
  int pr = (((widx >> 3) << 3) + (s >> 3) + 4) & 63;
  int pc = (((widx & 7) << 3) + (s & 7) + 4) & 63;
  return ((b << 12) | (pr << 6) | pc) << 9;
}

__device__ __forceinline__ f16x8 cvt8(float4 a, float4 b) {
  f16x8 h = { (f16)a.x, (f16)a.y, (f16)a.z, (f16)a.w,
              (f16)b.x, (f16)b.y, (f16)b.z, (f16)b.w };
  return h;
}

// ---------------------------------------------------------------------------
// Kernel 0: weight fp32 -> f16 with slot swizzle.  131072 threads, 8 elems each.
// ---------------------------------------------------------------------------
__global__ __launch_bounds__(256) void k_wcvt(const float* __restrict__ wq,
                                              const float* __restrict__ wo) {
  int idx = blockIdx.x * 256 + threadIdx.x;  // 0..131071
  const float* src;
  f16* dst;
  if (idx < 98304) { src = wq; dst = g_wq16; }
  else { idx -= 98304; src = wo; dst = g_wo16; }
  const int n = idx >> 6, kb = (idx >> 3) & 7, s = idx & 7;
  const float* p = src + n * 512 + kb * 64 + ((s ^ (n & 7)) << 3);
  float4 a = *(const float4*)(p);
  float4 b = *(const float4*)(p + 4);
  *(f16x8*)(dst + n * 512 + kb * 64 + s * 8) = cvt8(a, b);
}

// ---------------------------------------------------------------------------
// Kernel 1: QKV projection.  256 blocks x 512 thr (8 waves, 32 rows each).
// A (256x512 panel) gathered from x once into af[2][16] regs.
// B: BK=64 dbuf (2x16KB), staged via 2 gload_lds/wave (pre-swizzled source);
// per period: issue next-buffer DMA, 2 sub-steps x {8 ds_read + 16 MFMA}, sync.
// ---------------------------------------------------------------------------
__global__ __launch_bounds__(512, 2) void k_qkv(const float* __restrict__ x,
                                                const float* __restrict__ bq,
                                                f16* __restrict__ qk,
                                                f16* __restrict__ vt) {
  __shared__ __align__(16) char smem[102400];  // B0|B1 16KB each + 8 x 8704B Cw
  f16* const B0 = (f16*)smem;
  f16* const B1 = (f16*)(smem + 16384);

  const int tid = threadIdx.x;
  const int lane = tid & 63, wave = tid >> 6;
  const int jlo = lane & 15, g = lane >> 4;
  const int bm = blockIdx.x;  // 256 panels of 256 tokens

  // ---- A panel -> registers (gather + cvt), af[mt][ks] (R7 verbatim) ----
  const int r0 = tok2patch(bm * 256 + wave * 32 + jlo);
  const int r1 = tok2patch(bm * 256 + wave * 32 + 16 + jlo);
  f16x8 af[2][16];
#pragma unroll
  for (int kg = 0; kg < 4; ++kg) {
    float4 t0[4][2], t1[4][2];
#pragma unroll
    for (int k4 = 0; k4 < 4; ++k4) {
      const int ko = (kg * 4 + k4) * 32 + g * 8;
      t0[k4][0] = *(const float4*)(x + r0 + ko);
      t0[k4][1] = *(const float4*)(x + r0 + ko + 4);
      t1[k4][0] = *(const float4*)(x + r1 + ko);
      t1[k4][1] = *(const float4*)(x + r1 + ko + 4);
    }
#pragma unroll
    for (int k4 = 0; k4 < 4; ++k4) {
      af[0][kg * 4 + k4] = cvt8(t0[k4][0], t0[k4][1]);
      af[1][kg * 4 + k4] = cvt8(t1[k4][0], t1[k4][1]);
    }
    SCHEDBAR();
  }

  // B staging geometry: wave slab = tile rows [wave*16, +16); 2 x 1KB DMA.
  // per-lane source term: row += lane>>3, 16B slot = lane&7 (slot content
  // pre-swizzled in g_wq16, so LDS ends up [row][slot]=chunk slot^(row&7)).
  const f16* const bsrc = g_wq16 + (wave * 16 + (lane >> 3)) * 512 + (lane & 7) * 8;
  f16* const bdst = wave * 1024 + (f16*)nullptr;  // offset in f16 elems (added below)

  f32x4 acc[2][8] = {};

#define STAGE(P, Bp)                                                     \
  do {                                                                   \
    const f16* s_ = bsrc + ((P) >> 3) * 65536 + ((P) & 7) * 64;          \
    gl_lds16(s_, (Bp) + wave * 1024);                                    \
    gl_lds16(s_ + 8 * 512, (Bp) + wave * 1024 + 512);                    \
  } while (0)

  STAGE(0, B0);
  __syncthreads();

#pragma unroll 1
  for (int p = 0; p < 96; ++p) {
    f16* const Bc = (p & 1) ? B1 : B0;
    f16* const Bn = (p & 1) ? B0 : B1;
    if (p < 95) STAGE(p + 1, Bn);
#pragma unroll
    for (int s2 = 0; s2 < 2; ++s2) {
      const int ks = (p & 7) * 2 + s2;
      f16x8 bf[8];
#pragma unroll
      for (int nt = 0; nt < 8; ++nt) {
        const int n = nt * 16 + jlo;
        const int slot = (s2 * 4 + g) ^ (n & 7);
        bf[nt] = *(const f16x8*)(Bc + n * 64 + slot * 8);
      }
      __builtin_amdgcn_s_setprio(1);
#pragma unroll
      for (int mt = 0; mt < 2; ++mt)
#pragma unroll
        for (int nt = 0; nt < 8; ++nt)
          acc[mt][nt] = MFMA16(af[mt][ks], bf[nt], acc[mt][nt]);
      __builtin_amdgcn_s_setprio(0);
    }
    __syncthreads();  // drains next-buffer DMA + guards buffer swap

    if ((p & 7) == 7) {  // ---- epilogue for bn tile (R7 logic, byte-exact Cw) ----
      const int bn = p >> 3;
      float bias[8];
#pragma unroll
      for (int nt = 0; nt < 8; ++nt) bias[nt] = bq[bn * 128 + nt * 16 + jlo];
      if (bn < 8) {  // q or k: token rows, Cw 32x136 f16 (8704 B/wave)
        f16* const Cw = (f16*)(smem + 32768 + wave * 8704);
#pragma unroll
        for (int mt = 0; mt < 2; ++mt)
#pragma unroll
          for (int nt = 0; nt < 8; ++nt)
#pragma unroll
            for (int r = 0; r < 4; ++r)
              Cw[(mt * 16 + g * 4 + r) * 136 + nt * 16 + jlo] =
                  (f16)(acc[mt][nt][r] + bias[nt]);
        LGKM0();
        f16* const gb = (bn < 4) ? (qk + bn * 128) : (qk + QK_HALF + (bn - 4) * 128);
#pragma unroll
        for (int q = 0; q < 8; ++q) {
          const int lr = (q >> 1) * 8 + (lane >> 3);
          const int ch = (q & 1) * 8 + (lane & 7);
          const int trow = bm * 256 + wave * 32 + lr;
          *(f16x8*)(gb + trow * 512 + ch * 8) = *(const f16x8*)(Cw + lr * 136 + ch * 8);
        }
        LGKM0();
      } else {  // v: transpose to vt[w][h][d][s], Cw 64x48 f16 per half
        f16* const Cw = (f16*)(smem + 32768 + wave * 8704);
        const int w = bm * 4 + (wave >> 1);
        const int s0 = (wave * 32) & 63;
#pragma unroll
        for (int hf = 0; hf < 2; ++hf) {
#pragma unroll
          for (int n2 = 0; n2 < 4; ++n2) {
            const int nt = hf * 4 + n2;
#pragma unroll
            for (int mt = 0; mt < 2; ++mt) {
              f16x4 pk = { (f16)(acc[mt][nt][0] + bias[nt]), (f16)(acc[mt][nt][1] + bias[nt]),
                           (f16)(acc[mt][nt][2] + bias[nt]), (f16)(acc[mt][nt][3] + bias[nt]) };
              *(f16x4*)(Cw + (n2 * 16 + jlo) * 48 + mt * 16 + g * 4) = pk;
            }
          }
          LGKM0();
#pragma unroll
          for (int q = 0; q < 4; ++q) {
            const int cl = q * 16 + (lane >> 2);  // local col 0..63
            const int ch = lane & 3;
            const int n = (bn - 8) * 128 + hf * 64 + cl;
            const int h = n >> 5, d = n & 31;
            *(f16x8*)(vt + ((w * 16 + h) * 32 + d) * 64 + s0 + ch * 8) =
                *(const f16x8*)(Cw + cl * 48 + ch * 8);
          }
          LGKM0();
        }
      }
#pragma unroll
      for (int mt = 0; mt < 2; ++mt)
#pragma unroll
        for (int nt = 0; nt < 8; ++nt)
          acc[mt][nt] = (f32x4){0.f, 0.f, 0.f, 0.f};
    }
  }
#undef STAGE
}

// ---------------------------------------------------------------------------
// Kernel 2: per-window attention (verified, unchanged from R7).
// ---------------------------------------------------------------------------
__global__ __launch_bounds__(256) void k_attn(const f16* __restrict__ qk,
                                              const f16* __restrict__ vt,
                                              f16* __restrict__ ao) {
  __shared__ f16 P[4][64 * 72];
  const int w = blockIdx.x;
  const int widx = w & 63;
  const bool er = (widx >> 3) == 7;
  const bool ec = (widx & 7) == 7;
  const int tid = threadIdx.x;
  const int lane = tid & 63, wave = tid >> 6;
  const int jlo = lane & 15, g = lane >> 4;
  const int tb = w * 64;
  f16* Pw = P[wave];
  const float scale = 0.17677669529663687f;

#pragma unroll 1
  for (int hh = 0; hh < 4; ++hh) {
    const int h = wave * 4 + hh;
    f16x8 qa[4], kb[4];
#pragma unroll
    for (int mt = 0; mt < 4; ++mt)
      qa[mt] = *(const f16x8*)(qk + (tb + mt * 16 + jlo) * 512 + h * 32 + g * 8);
#pragma unroll
    for (int nt = 0; nt < 4; ++nt)
      kb[nt] = *(const f16x8*)(qk + QK_HALF + (tb + nt * 16 + jlo) * 512 + h * 32 + g * 8);
    f32x4 sc[4][4] = {};
#pragma unroll
    for (int mt = 0; mt < 4; ++mt)
#pragma unroll
      for (int nt = 0; nt < 4; ++nt)
        sc[mt][nt] = MFMA16(qa[mt], kb[nt], sc[mt][nt]);

    int gj[4];
#pragma unroll
    for (int nt = 0; nt < 4; ++nt) {
      int j = nt * 16 + jlo;
      gj[nt] = ((er && ((j >> 3) >= 4)) ? 2 : 0) | ((ec && ((j & 7) >= 4)) ? 1 : 0);
    }
    float rinv[4][4];
#pragma unroll
    for (int mt = 0; mt < 4; ++mt) {
#pragma unroll
      for (int r = 0; r < 4; ++r) {
        const int i = mt * 16 + g * 4 + r;
        const int gi = ((er && ((i >> 3) >= 4)) ? 2 : 0) | ((ec && ((i & 7) >= 4)) ? 1 : 0);
        float v0 = (gi == gj[0]) ? sc[mt][0][r] * scale : -1e9f;
        float v1 = (gi == gj[1]) ? sc[mt][1][r] * scale : -1e9f;
        float v2 = (gi == gj[2]) ? sc[mt][2][r] * scale : -1e9f;
        float v3 = (gi == gj[3]) ? sc[mt][3][r] * scale : -1e9f;
        float m = fmaxf(fmaxf(v0, v1), fmaxf(v2, v3));
        m = fmaxf(m, __shfl_xor(m, 1));
        m = fmaxf(m, __shfl_xor(m, 2));
        m = fmaxf(m, __shfl_xor(m, 4));
        m = fmaxf(m, __shfl_xor(m, 8));
        float p0 = __expf(v0 - m), p1 = __expf(v1 - m);
        float p2 = __expf(v2 - m), p3 = __expf(v3 - m);
        float s = p0 + p1 + p2 + p3;
        s += __shfl_xor(s, 1);
        s += __shfl_xor(s, 2);
        s += __shfl_xor(s, 4);
        s += __shfl_xor(s, 8);
        rinv[mt][r] = 1.0f / s;
        sc[mt][0][r] = p0; sc[mt][1][r] = p1; sc[mt][2][r] = p2; sc[mt][3][r] = p3;
      }
    }
#pragma unroll
    for (int mt = 0; mt < 4; ++mt)
#pragma unroll
      for (int nt = 0; nt < 4; ++nt)
#pragma unroll
        for (int r = 0; r < 4; ++r)
          Pw[(mt * 16 + g * 4 + r) * 72 + nt * 16 + jlo] = (f16)sc[mt][nt][r];
    asm volatile("s_waitcnt lgkmcnt(0)" ::: "memory");

    f32x4 o[4][2] = {};
#pragma unroll
    for (int ks = 0; ks < 2; ++ks) {
      f16x8 pa[4], vb[2];
#pragma unroll
      for (int mt = 0; mt < 4; ++mt)
        pa[mt] = *(const f16x8*)((const char*)Pw + (mt * 16 + jlo) * 144 + ks * 64 + g * 16);
#pragma unroll
      for (int nt = 0; nt < 2; ++nt)
        vb[nt] = *(const f16x8*)(vt + ((w * 16 + h) * 32 + nt * 16 + jlo) * 64 + ks * 32 + g * 8);
#pragma unroll
      for (int mt = 0; mt < 4; ++mt)
#pragma unroll
        for (int nt = 0; nt < 2; ++nt)
          o[mt][nt] = MFMA16(pa[mt], vb[nt], o[mt][nt]);
    }
#pragma unroll
    for (int mt = 0; mt < 4; ++mt)
#pragma unroll
      for (int nt = 0; nt < 2; ++nt)
#pragma unroll
        for (int r = 0; r < 4; ++r)
          Pw[(mt * 16 + g * 4 + r) * 40 + nt * 16 + jlo] =
              (f16)(o[mt][nt][r] * rinv[mt][r]);
    f16* arow = ao + (tb + lane) * 512 + h * 32;
#pragma unroll
    for (int c = 0; c < 4; ++c)
      *(f16x8*)(arow + c * 8) = *(const f16x8*)(Pw + lane * 40 + c * 8);
  }
}

// ---------------------------------------------------------------------------
// Kernel 3: output projection.  Same structure as k_qkv (A=ao in regs,
// B=g_wo16 via gload_lds, 4 bn tiles, 32 periods), NT stores on final out.
// ---------------------------------------------------------------------------
__global__ __launch_bounds__(512, 2) void k_out(const f16* __restrict__ ao,
                                                const float* __restrict__ bo,
                                                float* __restrict__ out) {
  __shared__ __align__(16) char smem[102400];  // B0|B1 16KB + 8 x 8704B Cw(f32)
  f16* const B0 = (f16*)smem;
  f16* const B1 = (f16*)(smem + 16384);

  const int tid = threadIdx.x;
  const int lane = tid & 63, wave = tid >> 6;
  const int jlo = lane & 15, g = lane >> 4;
  const int bm = blockIdx.x;  // 256 panels

  // A frags straight from ao (f16, contiguous)
  const f16* const a0 = ao + (bm * 256 + wave * 32 + jlo) * 512 + g * 8;
  const f16* const a1 = a0 + 16 * 512;
  f16x8 af[2][16];
#pragma unroll
  for (int ks = 0; ks < 16; ++ks) {
    af[0][ks] = *(const f16x8*)(a0 + ks * 32);
    af[1][ks] = *(const f16x8*)(a1 + ks * 32);
  }

  const f16* const bsrc = g_wo16 + (wave * 16 + (lane >> 3)) * 512 + (lane & 7) * 8;
  f32x4 acc[2][8] = {};

#define STAGE(P, Bp)                                                     \
  do {                                                                   \
    const f16* s_ = bsrc + ((P) >> 3) * 65536 + ((P) & 7) * 64;          \
    gl_lds16(s_, (Bp) + wave * 1024);                                    \
    gl_lds16(s_ + 8 * 512, (Bp) + wave * 1024 + 512);                    \
  } while (0)

  STAGE(0, B0);
  __syncthreads();

#pragma unroll 1
  for (int p = 0; p < 32; ++p) {
    f16* const Bc = (p & 1) ? B1 : B0;
    f16* const Bn = (p & 1) ? B0 : B1;
    if (p < 31) STAGE(p + 1, Bn);
#pragma unroll
    for (int s2 = 0; s2 < 2; ++s2) {
      const int ks = (p & 7) * 2 + s2;
      f16x8 bf[8];
#pragma unroll
      for (int nt = 0; nt < 8; ++nt) {
        const int n = nt * 16 + jlo;
        const int slot = (s2 * 4 + g) ^ (n & 7);
        bf[nt] = *(const f16x8*)(Bc + n * 64 + slot * 8);
      }
      __builtin_amdgcn_s_setprio(1);
#pragma unroll
      for (int mt = 0; mt < 2; ++mt)
#pragma unroll
        for (int nt = 0; nt < 8; ++nt)
          acc[mt][nt] = MFMA16(af[mt][ks], bf[nt], acc[mt][nt]);
      __builtin_amdgcn_s_setprio(0);
    }
    __syncthreads();

    if ((p & 7) == 7) {  // epilogue: fp32 scatter via tok2patch (NT), 2 halves
      const int bn = p >> 3;
      float* const Cw = (float*)(smem + 32768 + wave * 8704);  // 32 x 68 f32
#pragma unroll
      for (int hf = 0; hf < 2; ++hf) {
#pragma unroll
        for (int n2 = 0; n2 < 4; ++n2) {
          const int nt = hf * 4 + n2;
          const float bias = bo[bn * 128 + nt * 16 + jlo];
#pragma unroll
          for (int mt = 0; mt < 2; ++mt)
#pragma unroll
            for (int r = 0; r < 4; ++r)
              Cw[(mt * 16 + g * 4 + r) * 68 + n2 * 16 + jlo] = acc[mt][nt][r] + bias;
        }
        LGKM0();
#pragma unroll
        for (int q = 0; q < 8; ++q) {
          const int lr = (q >> 1) * 8 + (lane >> 3);
          const int ch = (q & 1) * 8 + (lane & 7);
          const int trow = bm * 256 + wave * 32 + lr;
          nts4f(*(const f32x4*)(Cw + lr * 68 + ch * 4),
                out + tok2patch(trow) + bn * 128 + hf * 64 + ch * 4);
        }
        LGKM0();
      }
#pragma unroll
      for (int mt = 0; mt < 2; ++mt)
#pragma unroll
        for (int nt = 0; nt < 8; ++nt)
          acc[mt][nt] = (f32x4){0.f, 0.f, 0.f, 0.f};
    }
  }
#undef STAGE
}

extern "C" void kernel_launch(void* const* d_in, const int* in_sizes, int n_in,
                              void* d_out, int out_size, void* d_ws, size_t ws_size,
                              hipStream_t stream) {
  const float* x  = (const float*)d_in[0];
  const float* wq = (const float*)d_in[1];
  const float* bq = (const float*)d_in[2];
  const float* wo = (const float*)d_in[3];
  const float* bo = (const float*)d_in[4];
  float* out = (float*)d_out;

  f16* qk = (f16*)d_out;                        // q|k overlay (128 MiB)
  f16* ao = (f16*)d_ws;                         // attention output (64 MiB)
  f16* vt = (f16*)((char*)d_ws + (64u << 20));  // V transposed (64 MiB)

  k_wcvt<<<dim3(512), 256, 0, stream>>>(wq, wo);
  k_qkv<<<dim3(256), 512, 0, stream>>>(x, bq, qk, vt);
  k_attn<<<dim3(1024), 256, 0, stream>>>(qk, vt, ao);
  k_out<<<dim3(256), 512, 0, stream>>>(ao, bo, out);
}

// Round 11
// 425.632 us; speedup vs baseline: 1.0476x; 1.0476x over previous
//
#include <hip/hip_runtime.h>

// Swin shifted-window attention, MI355X gfx950.  R10 = R7 base + BK=128 barrier
// periods (64 MFMA/wave per barrier, 4x fewer rendezvous; B dbuf 2x32KB,
// two half-commits per period with 1-period-lookahead reg staging).
// k_qkv (A-in-reg gather GEMM) -> k_attn -> k_out (A=ao in regs, NT out).
// d_out holds q|k f16 overlay until k_out overwrites it (fp32).
// ws: [0,64MiB) ao; [64,128MiB) vt.

using f16   = _Float16;
using f16x8 = __attribute__((ext_vector_type(8))) _Float16;
using f16x4 = __attribute__((ext_vector_type(4))) _Float16;
using f32x4 = __attribute__((ext_vector_type(4))) float;

#define MFMA16(a, b, c) __builtin_amdgcn_mfma_f32_16x16x32_f16((a), (b), (c), 0, 0, 0)
#define SCHEDBAR() __builtin_amdgcn_sched_barrier(0)
#define VMCNT0() asm volatile("s_waitcnt vmcnt(0)" ::: "memory")
#define LGKM0()  asm volatile("s_waitcnt lgkmcnt(0)" ::: "memory")
#define BAR()    __builtin_amdgcn_s_barrier()

static constexpr int QK_HALF = 65536 * 512;

__device__ __forceinline__ void nts4f(f32x4 v, float* p) {
  __builtin_nontemporal_store(v, (f32x4*)p);
}

__device__ __forceinline__ int tok2patch(int t) {
  int b = t >> 12, rem = t & 4095;
  int widx = rem >> 6, s = rem & 63;
  int pr = (((widx >> 3) << 3) + (s >> 3) + 4) & 63;
  int pc = (((widx & 7) << 3) + (s & 7) + 4) & 63;
  return ((b << 12) | (pr << 6) | pc) << 9;
}

__device__ __forceinline__ f16x8 cvt8(float4 a, float4 b) {
  f16x8 h = { (f16)a.x, (f16)a.y, (f16)a.z, (f16)a.w,
              (f16)b.x, (f16)b.y, (f16)b.z, (f16)b.w };
  return h;
}

// ---------------------------------------------------------------------------
// Kernel 1: QKV projection.  256 blocks x 512 thr (8 waves, 32 rows each).
// A (256x512 panel) gathered from x once into af[2][16] regs (R7 verbatim).
// B: BK=128 dbuf (2x32KB).  Per period p (48 total = 12 bn x 4):
//   [substeps 0-1: 16 bf reads + 32 MFMA]
//   VMCNT0; WRITEB(p+1,h0); LOADB(p+1,h1)
//   [substeps 2-3]
//   VMCNT0; WRITEB(p+1,h1); LOADB(p+2,h0); LGKM0; BAR
// B row = 256B (16 slots of 16B), slot stored at s^(row&7) (read matches).
// ---------------------------------------------------------------------------
__global__ __launch_bounds__(512, 2) void k_qkv(const float* __restrict__ x,
                                                const float* __restrict__ wq,
                                                const float* __restrict__ bq,
                                                f16* __restrict__ qk,
                                                f16* __restrict__ vt) {
  __shared__ __align__(16) char smem[135168];  // B0|B1 32KB each + 8 x 8704B Cw
  f16* const B0 = (f16*)smem;
  f16* const B1 = (f16*)(smem + 32768);

  const int tid = threadIdx.x;
  const int lane = tid & 63, wave = tid >> 6;
  const int jlo = lane & 15, g = lane >> 4;
  const int bm = blockIdx.x;  // 256 panels of 256 tokens

  // ---- A panel -> registers (gather + cvt), af[mt][ks] ----
  const int r0 = tok2patch(bm * 256 + wave * 32 + jlo);
  const int r1 = tok2patch(bm * 256 + wave * 32 + 16 + jlo);
  f16x8 af[2][16];
#pragma unroll
  for (int kg = 0; kg < 4; ++kg) {
    float4 t0[4][2], t1[4][2];
#pragma unroll
    for (int k4 = 0; k4 < 4; ++k4) {
      const int ko = (kg * 4 + k4) * 32 + g * 8;
      t0[k4][0] = *(const float4*)(x + r0 + ko);
      t0[k4][1] = *(const float4*)(x + r0 + ko + 4);
      t1[k4][0] = *(const float4*)(x + r1 + ko);
      t1[k4][1] = *(const float4*)(x + r1 + ko + 4);
    }
#pragma unroll
    for (int k4 = 0; k4 < 4; ++k4) {
      af[0][kg * 4 + k4] = cvt8(t0[k4][0], t0[k4][1]);
      af[1][kg * 4 + k4] = cvt8(t1[k4][0], t1[k4][1]);
    }
    SCHEDBAR();
  }

  // B staging: thread covers row nl (0..127), k-quarter kq (32 fp32 = 2 slots)
  const int nl = tid >> 2, kq = tid & 3;
  const int s0w = kq * 2;  // base slot within half (h adds 8)
  f32x4 acc[2][8] = {};
  float4 rb[4];

  // LOADB(period P, half h): 4 float4 from wq row, k = (P&3)*128 + h*64 + kq*16
#define LOADB(P, H)                                                          \
  do {                                                                       \
    const float* bs_ = wq + (((P) >> 2) * 128 + nl) * 512 +                  \
                       ((P) & 3) * 128 + (H) * 64 + kq * 16;                 \
    rb[0] = *(const float4*)(bs_);      rb[1] = *(const float4*)(bs_ + 4);   \
    rb[2] = *(const float4*)(bs_ + 8);  rb[3] = *(const float4*)(bs_ + 12);  \
  } while (0)
  // WRITEB(buffer, half): 2 x f16x8 at slots (h*8+s0w(+1)) ^ (nl&7)
#define WRITEB(Bp, H)                                                        \
  do {                                                                       \
    *(f16x8*)((Bp) + nl * 128 + ((((H) * 8 + s0w)     ^ (nl & 7)) * 8)) =    \
        cvt8(rb[0], rb[1]);                                                  \
    *(f16x8*)((Bp) + nl * 128 + ((((H) * 8 + s0w + 1) ^ (nl & 7)) * 8)) =    \
        cvt8(rb[2], rb[3]);                                                  \
  } while (0)

  // prologue: stage period 0 fully, put (1,h0) in flight
  LOADB(0, 0); SCHEDBAR(); VMCNT0(); WRITEB(B0, 0);
  LOADB(0, 1); SCHEDBAR(); VMCNT0(); WRITEB(B0, 1);
  LOADB(1, 0); SCHEDBAR();
  LGKM0();
  BAR();

#pragma unroll 1
  for (int p = 0; p < 48; ++p) {
    f16* const Bc = (p & 1) ? B1 : B0;
    f16* const Bn = (p & 1) ? B0 : B1;

#pragma unroll
    for (int half = 0; half < 2; ++half) {
#pragma unroll
      for (int s2 = 0; s2 < 2; ++s2) {
        const int ks = half * 2 + s2;          // sub-step 0..3 (K32 each)
        const int kst = (p & 3) * 4 + ks;      // global K32 index 0..15
        f16x8 bf[8];
#pragma unroll
        for (int nt = 0; nt < 8; ++nt) {
          const int n = nt * 16 + jlo;
          const int slot = (ks * 4 + g) ^ (n & 7);
          bf[nt] = *(const f16x8*)(Bc + n * 128 + slot * 8);
        }
        __builtin_amdgcn_s_setprio(1);
#pragma unroll
        for (int mt = 0; mt < 2; ++mt)
#pragma unroll
          for (int nt = 0; nt < 8; ++nt)
            acc[mt][nt] = MFMA16(af[mt][kst], bf[nt], acc[mt][nt]);
        __builtin_amdgcn_s_setprio(0);
      }
      // staging checkpoint after each half's compute
      if (half == 0) {
        if (p < 47) {
          VMCNT0();            // LOADB(p+1, h0) landed (issued last period)
          WRITEB(Bn, 0);
          SCHEDBAR();
          LOADB(p + 1, 1);
          SCHEDBAR();
        }
      } else {
        if (p < 47) {
          VMCNT0();            // LOADB(p+1, h1) landed
          WRITEB(Bn, 1);
          SCHEDBAR();
          if (p < 46) { LOADB(p + 2, 0); SCHEDBAR(); }
        }
        LGKM0();
        BAR();
      }
    }

    if ((p & 3) == 3) {  // ---- epilogue for bn tile (R7 logic) ----
      const int bn = p >> 2;
      float bias[8];
#pragma unroll
      for (int nt = 0; nt < 8; ++nt) bias[nt] = bq[bn * 128 + nt * 16 + jlo];
      if (bn < 8) {  // q or k: token rows, Cw 32x136 f16 (8704 B/wave)
        f16* const Cw = (f16*)(smem + 65536 + wave * 8704);
#pragma unroll
        for (int mt = 0; mt < 2; ++mt)
#pragma unroll
          for (int nt = 0; nt < 8; ++nt)
#pragma unroll
            for (int r = 0; r < 4; ++r)
              Cw[(mt * 16 + g * 4 + r) * 136 + nt * 16 + jlo] =
                  (f16)(acc[mt][nt][r] + bias[nt]);
        LGKM0();
        f16* const gb = (bn < 4) ? (qk + bn * 128) : (qk + QK_HALF + (bn - 4) * 128);
#pragma unroll
        for (int q = 0; q < 8; ++q) {
          const int lr = (q >> 1) * 8 + (lane >> 3);
          const int ch = (q & 1) * 8 + (lane & 7);
          const int trow = bm * 256 + wave * 32 + lr;
          *(f16x8*)(gb + trow * 512 + ch * 8) = *(const f16x8*)(Cw + lr * 136 + ch * 8);
        }
        LGKM0();
      } else {  // v: transpose to vt[w][h][d][s], Cw 64x48 f16 per half
        f16* const Cw = (f16*)(smem + 65536 + wave * 8704);
        const int w = bm * 4 + (wave >> 1);
        const int s0 = (wave * 32) & 63;
#pragma unroll
        for (int hf = 0; hf < 2; ++hf) {
#pragma unroll
          for (int n2 = 0; n2 < 4; ++n2) {
            const int nt = hf * 4 + n2;
#pragma unroll
            for (int mt = 0; mt < 2; ++mt) {
              f16x4 pk = { (f16)(acc[mt][nt][0] + bias[nt]), (f16)(acc[mt][nt][1] + bias[nt]),
                           (f16)(acc[mt][nt][2] + bias[nt]), (f16)(acc[mt][nt][3] + bias[nt]) };
              *(f16x4*)(Cw + (n2 * 16 + jlo) * 48 + mt * 16 + g * 4) = pk;
            }
          }
          LGKM0();
#pragma unroll
          for (int q = 0; q < 4; ++q) {
            const int cl = q * 16 + (lane >> 2);
            const int ch = lane & 3;
            const int n = (bn - 8) * 128 + hf * 64 + cl;
            const int h = n >> 5, d = n & 31;
            *(f16x8*)(vt + ((w * 16 + h) * 32 + d) * 64 + s0 + ch * 8) =
                *(const f16x8*)(Cw + cl * 48 + ch * 8);
          }
          LGKM0();
        }
      }
#pragma unroll
      for (int mt = 0; mt < 2; ++mt)
#pragma unroll
        for (int nt = 0; nt < 8; ++nt)
          acc[mt][nt] = (f32x4){0.f, 0.f, 0.f, 0.f};
    }
  }
#undef LOADB
#undef WRITEB
}

// ---------------------------------------------------------------------------
// Kernel 2: per-window attention (verified, unchanged).
// ---------------------------------------------------------------------------
__global__ __launch_bounds__(256) void k_attn(const f16* __restrict__ qk,
                                              const f16* __restrict__ vt,
                                              f16* __restrict__ ao) {
  __shared__ f16 P[4][64 * 72];
  const int w = blockIdx.x;
  const int widx = w & 63;
  const bool er = (widx >> 3) == 7;
  const bool ec = (widx & 7) == 7;
  const int tid = threadIdx.x;
  const int lane = tid & 63, wave = tid >> 6;
  const int jlo = lane & 15, g = lane >> 4;
  const int tb = w * 64;
  f16* Pw = P[wave];
  const float scale = 0.17677669529663687f;

#pragma unroll 1
  for (int hh = 0; hh < 4; ++hh) {
    const int h = wave * 4 + hh;
    f16x8 qa[4], kb[4];
#pragma unroll
    for (int mt = 0; mt < 4; ++mt)
      qa[mt] = *(const f16x8*)(qk + (tb + mt * 16 + jlo) * 512 + h * 32 + g * 8);
#pragma unroll
    for (int nt = 0; nt < 4; ++nt)
      kb[nt] = *(const f16x8*)(qk + QK_HALF + (tb + nt * 16 + jlo) * 512 + h * 32 + g * 8);
    f32x4 sc[4][4] = {};
#pragma unroll
    for (int mt = 0; mt < 4; ++mt)
#pragma unroll
      for (int nt = 0; nt < 4; ++nt)
        sc[mt][nt] = MFMA16(qa[mt], kb[nt], sc[mt][nt]);

    int gj[4];
#pragma unroll
    for (int nt = 0; nt < 4; ++nt) {
      int j = nt * 16 + jlo;
      gj[nt] = ((er && ((j >> 3) >= 4)) ? 2 : 0) | ((ec && ((j & 7) >= 4)) ? 1 : 0);
    }
    float rinv[4][4];
#pragma unroll
    for (int mt = 0; mt < 4; ++mt) {
#pragma unroll
      for (int r = 0; r < 4; ++r) {
        const int i = mt * 16 + g * 4 + r;
        const int gi = ((er && ((i >> 3) >= 4)) ? 2 : 0) | ((ec && ((i & 7) >= 4)) ? 1 : 0);
        float v0 = (gi == gj[0]) ? sc[mt][0][r] * scale : -1e9f;
        float v1 = (gi == gj[1]) ? sc[mt][1][r] * scale : -1e9f;
        float v2 = (gi == gj[2]) ? sc[mt][2][r] * scale : -1e9f;
        float v3 = (gi == gj[3]) ? sc[mt][3][r] * scale : -1e9f;
        float m = fmaxf(fmaxf(v0, v1), fmaxf(v2, v3));
        m = fmaxf(m, __shfl_xor(m, 1));
        m = fmaxf(m, __shfl_xor(m, 2));
        m = fmaxf(m, __shfl_xor(m, 4));
        m = fmaxf(m, __shfl_xor(m, 8));
        float p0 = __expf(v0 - m), p1 = __expf(v1 - m);
        float p2 = __expf(v2 - m), p3 = __expf(v3 - m);
        float s = p0 + p1 + p2 + p3;
        s += __shfl_xor(s, 1);
        s += __shfl_xor(s, 2);
        s += __shfl_xor(s, 4);
        s += __shfl_xor(s, 8);
        rinv[mt][r] = 1.0f / s;
        sc[mt][0][r] = p0; sc[mt][1][r] = p1; sc[mt][2][r] = p2; sc[mt][3][r] = p3;
      }
    }
#pragma unroll
    for (int mt = 0; mt < 4; ++mt)
#pragma unroll
      for (int nt = 0; nt < 4; ++nt)
#pragma unroll
        for (int r = 0; r < 4; ++r)
          Pw[(mt * 16 + g * 4 + r) * 72 + nt * 16 + jlo] = (f16)sc[mt][nt][r];
    asm volatile("s_waitcnt lgkmcnt(0)" ::: "memory");

    f32x4 o[4][2] = {};
#pragma unroll
    for (int ks = 0; ks < 2; ++ks) {
      f16x8 pa[4], vb[2];
#pragma unroll
      for (int mt = 0; mt < 4; ++mt)
        pa[mt] = *(const f16x8*)((const char*)Pw + (mt * 16 + jlo) * 144 + ks * 64 + g * 16);
#pragma unroll
      for (int nt = 0; nt < 2; ++nt)
        vb[nt] = *(const f16x8*)(vt + ((w * 16 + h) * 32 + nt * 16 + jlo) * 64 + ks * 32 + g * 8);
#pragma unroll
      for (int mt = 0; mt < 4; ++mt)
#pragma unroll
        for (int nt = 0; nt < 2; ++nt)
          o[mt][nt] = MFMA16(pa[mt], vb[nt], o[mt][nt]);
    }
#pragma unroll
    for (int mt = 0; mt < 4; ++mt)
#pragma unroll
      for (int nt = 0; nt < 2; ++nt)
#pragma unroll
        for (int r = 0; r < 4; ++r)
          Pw[(mt * 16 + g * 4 + r) * 40 + nt * 16 + jlo] =
              (f16)(o[mt][nt][r] * rinv[mt][r]);
    f16* arow = ao + (tb + lane) * 512 + h * 32;
#pragma unroll
    for (int c = 0; c < 4; ++c)
      *(f16x8*)(arow + c * 8) = *(const f16x8*)(Pw + lane * 40 + c * 8);
  }
}

// ---------------------------------------------------------------------------
// Kernel 3: output projection.  Same BK=128 period structure (16 periods),
// A=ao in regs, fp32 scatter via tok2patch (NT).
// ---------------------------------------------------------------------------
__global__ __launch_bounds__(512, 2) void k_out(const f16* __restrict__ ao,
                                                const float* __restrict__ wo,
                                                const float* __restrict__ bo,
                                                float* __restrict__ out) {
  __shared__ __align__(16) char smem[135168];
  f16* const B0 = (f16*)smem;
  f16* const B1 = (f16*)(smem + 32768);

  const int tid = threadIdx.x;
  const int lane = tid & 63, wave = tid >> 6;
  const int jlo = lane & 15, g = lane >> 4;
  const int bm = blockIdx.x;

  const f16* const a0 = ao + (bm * 256 + wave * 32 + jlo) * 512 + g * 8;
  const f16* const a1 = a0 + 16 * 512;
  f16x8 af[2][16];
#pragma unroll
  for (int ks = 0; ks < 16; ++ks) {
    af[0][ks] = *(const f16x8*)(a0 + ks * 32);
    af[1][ks] = *(const f16x8*)(a1 + ks * 32);
  }

  const int nl = tid >> 2, kq = tid & 3;
  const int s0w = kq * 2;
  f32x4 acc[2][8] = {};
  float4 rb[4];

#define LOADB(P, H)                                                          \
  do {                                                                       \
    const float* bs_ = wo + (((P) >> 2) * 128 + nl) * 512 +                  \
                       ((P) & 3) * 128 + (H) * 64 + kq * 16;                 \
    rb[0] = *(const float4*)(bs_);      rb[1] = *(const float4*)(bs_ + 4);   \
    rb[2] = *(const float4*)(bs_ + 8);  rb[3] = *(const float4*)(bs_ + 12);  \
  } while (0)
#define WRITEB(Bp, H)                                                        \
  do {                                                                       \
    *(f16x8*)((Bp) + nl * 128 + ((((H) * 8 + s0w)     ^ (nl & 7)) * 8)) =    \
        cvt8(rb[0], rb[1]);                                                  \
    *(f16x8*)((Bp) + nl * 128 + ((((H) * 8 + s0w + 1) ^ (nl & 7)) * 8)) =    \
        cvt8(rb[2], rb[3]);                                                  \
  } while (0)

  LOADB(0, 0); SCHEDBAR(); VMCNT0(); WRITEB(B0, 0);
  LOADB(0, 1); SCHEDBAR(); VMCNT0(); WRITEB(B0, 1);
  LOADB(1, 0); SCHEDBAR();
  LGKM0();
  BAR();

#pragma unroll 1
  for (int p = 0; p < 16; ++p) {
    f16* const Bc = (p & 1) ? B1 : B0;
    f16* const Bn = (p & 1) ? B0 : B1;

#pragma unroll
    for (int half = 0; half < 2; ++half) {
#pragma unroll
      for (int s2 = 0; s2 < 2; ++s2) {
        const int ks = half * 2 + s2;
        const int kst = (p & 3) * 4 + ks;
        f16x8 bf[8];
#pragma unroll
        for (int nt = 0; nt < 8; ++nt) {
          const int n = nt * 16 + jlo;
          const int slot = (ks * 4 + g) ^ (n & 7);
          bf[nt] = *(const f16x8*)(Bc + n * 128 + slot * 8);
        }
        __builtin_amdgcn_s_setprio(1);
#pragma unroll
        for (int mt = 0; mt < 2; ++mt)
#pragma unroll
          for (int nt = 0; nt < 8; ++nt)
            acc[mt][nt] = MFMA16(af[mt][kst], bf[nt], acc[mt][nt]);
        __builtin_amdgcn_s_setprio(0);
      }
      if (half == 0) {
        if (p < 15) {
          VMCNT0();
          WRITEB(Bn, 0);
          SCHEDBAR();
          LOADB(p + 1, 1);
          SCHEDBAR();
        }
      } else {
        if (p < 15) {
          VMCNT0();
          WRITEB(Bn, 1);
          SCHEDBAR();
          if (p < 14) { LOADB(p + 2, 0); SCHEDBAR(); }
        }
        LGKM0();
        BAR();
      }
    }

    if ((p & 3) == 3) {  // epilogue: fp32 scatter via tok2patch (NT), 2 halves
      const int bn = p >> 2;
      float* const Cw = (float*)(smem + 65536 + wave * 8704);  // 32 x 68 f32
#pragma unroll
      for (int hf = 0; hf < 2; ++hf) {
#pragma unroll
        for (int n2 = 0; n2 < 4; ++n2) {
          const int nt = hf * 4 + n2;
          const float bias = bo[bn * 128 + nt * 16 + jlo];
#pragma unroll
          for (int mt = 0; mt < 2; ++mt)
#pragma unroll
            for (int r = 0; r < 4; ++r)
              Cw[(mt * 16 + g * 4 + r) * 68 + n2 * 16 + jlo] = acc[mt][nt][r] + bias;
        }
        LGKM0();
#pragma unroll
        for (int q = 0; q < 8; ++q) {
          const int lr = (q >> 1) * 8 + (lane >> 3);
          const int ch = (q & 1) * 8 + (lane & 7);
          const int trow = bm * 256 + wave * 32 + lr;
          nts4f(*(const f32x4*)(Cw + lr * 68 + ch * 4),
                out + tok2patch(trow) + bn * 128 + hf * 64 + ch * 4);
        }
        LGKM0();
      }
#pragma unroll
      for (int mt = 0; mt < 2; ++mt)
#pragma unroll
        for (int nt = 0; nt < 8; ++nt)
          acc[mt][nt] = (f32x4){0.f, 0.f, 0.f, 0.f};
    }
  }
#undef LOADB
#undef WRITEB
}

extern "C" void kernel_launch(void* const* d_in, const int* in_sizes, int n_in,
                              void* d_out, int out_size, void* d_ws, size_t ws_size,
                              hipStream_t stream) {
  const float* x  = (const float*)d_in[0];
  const float* wq = (const float*)d_in[1];
  const float* bq = (const float*)d_in[2];
  const float* wo = (const float*)d_in[3];
  const float* bo = (const float*)d_in[4];
  float* out = (float*)d_out;

  f16* qk = (f16*)d_out;                        // q|k overlay (128 MiB)
  f16* ao = (f16*)d_ws;                         // attention output (64 MiB)
  f16* vt = (f16*)((char*)d_ws + (64u << 20));  // V transposed (64 MiB)

  k_qkv<<<dim3(256), 512, 0, stream>>>(x, wq, bq, qk, vt);
  k_attn<<<dim3(1024), 256, 0, stream>>>(qk, vt, ao);
  k_out<<<dim3(256), 512, 0, stream>>>(ao, wo, bo, out);
}

// Round 12
// 407.449 us; speedup vs baseline: 1.0943x; 1.0446x over previous
//
#include <hip/hip_runtime.h>

// Swin shifted-window attention, MI355X gfx950.  R11: FUSED qkv+attention.
// k_fused: 256 blocks x 512 thr; per block = 256 tokens = 4 windows.
//   A (x rows) gathered once into af[2][16] regs (R7-verified).
//   Loop over 8 head-groups (2 heads = 64 cols): 3 GEMM tiles (q,k,v) with
//   BK=128 double-buffered B staging -> LDS (q,k row-major [256][72]; v
//   transposed [win][hh][d][72]); then inline per-window attention (verified
//   k_attn math; P via Pw overlay of dead q+k, stride 72), writing only ao.
// k_out: R7-verified output projection (A=ao in regs, NT scatter stores).
// ws: [0,64MiB) ao.  qk/vt intermediates eliminated (-384MB HBM traffic).

using f16   = _Float16;
using f16x8 = __attribute__((ext_vector_type(8))) _Float16;
using f16x4 = __attribute__((ext_vector_type(4))) _Float16;
using f32x4 = __attribute__((ext_vector_type(4))) float;

#define MFMA16(a, b, c) __builtin_amdgcn_mfma_f32_16x16x32_f16((a), (b), (c), 0, 0, 0)
#define SCHEDBAR() __builtin_amdgcn_sched_barrier(0)
#define VMCNT0() asm volatile("s_waitcnt vmcnt(0)" ::: "memory")
#define LGKM0()  asm volatile("s_waitcnt lgkmcnt(0)" ::: "memory")
#define BAR()    __builtin_amdgcn_s_barrier()

__device__ __forceinline__ void nts4f(f32x4 v, float* p) {
  __builtin_nontemporal_store(v, (f32x4*)p);
}

__device__ __forceinline__ int tok2patch(int t) {
  int b = t >> 12, rem = t & 4095;
  int widx = rem >> 6, s = rem & 63;
  int pr = (((widx >> 3) << 3) + (s >> 3) + 4) & 63;
  int pc = (((widx & 7) << 3) + (s & 7) + 4) & 63;
  return ((b << 12) | (pr << 6) | pc) << 9;
}

__device__ __forceinline__ f16x8 cvt8(float4 a, float4 b) {
  f16x8 h = { (f16)a.x, (f16)a.y, (f16)a.z, (f16)a.w,
              (f16)b.x, (f16)b.y, (f16)b.z, (f16)b.w };
  return h;
}

// ---------------------------------------------------------------------------
// Kernel 1: fused QKV + windowed attention.
// LDS map (bytes): Q[256][72] @0 (36864) | K[256][72] @36864 | V[8][32][72]
// @73728 | B0 @110592 (16KB) | B1 @126976 (16KB).  Pw(wave) = 9216B overlay
// of Q+K (dead during attention).  96 GEMM periods = 8 hg x 3 tiles x 4.
// ---------------------------------------------------------------------------
__global__ __launch_bounds__(512, 2) void k_fused(const float* __restrict__ x,
                                                  const float* __restrict__ wq,
                                                  const float* __restrict__ bq,
                                                  f16* __restrict__ ao) {
  __shared__ __align__(16) char smem[143360];
  f16* const Q  = (f16*)smem;
  f16* const Kl = (f16*)(smem + 36864);
  f16* const V  = (f16*)(smem + 73728);
  f16* const B0 = (f16*)(smem + 110592);
  f16* const B1 = (f16*)(smem + 126976);

  const int tid = threadIdx.x;
  const int lane = tid & 63, wave = tid >> 6;
  const int jlo = lane & 15, g = lane >> 4;
  const int bm = blockIdx.x;  // 256 panels of 256 tokens = 4 windows

  // ---- A panel -> registers (gather + cvt), af[mt][ks] (R7 verbatim) ----
  const int r0 = tok2patch(bm * 256 + wave * 32 + jlo);
  const int r1 = tok2patch(bm * 256 + wave * 32 + 16 + jlo);
  f16x8 af[2][16];
#pragma unroll
  for (int kg = 0; kg < 4; ++kg) {
    float4 t0[4][2], t1[4][2];
#pragma unroll
    for (int k4 = 0; k4 < 4; ++k4) {
      const int ko = (kg * 4 + k4) * 32 + g * 8;
      t0[k4][0] = *(const float4*)(x + r0 + ko);
      t0[k4][1] = *(const float4*)(x + r0 + ko + 4);
      t1[k4][0] = *(const float4*)(x + r1 + ko);
      t1[k4][1] = *(const float4*)(x + r1 + ko + 4);
    }
#pragma unroll
    for (int k4 = 0; k4 < 4; ++k4) {
      af[0][kg * 4 + k4] = cvt8(t0[k4][0], t0[k4][1]);
      af[1][kg * 4 + k4] = cvt8(t1[k4][0], t1[k4][1]);
    }
    SCHEDBAR();
  }

  // B staging: tile = 64 wqkv rows x 128 K.  Thread: row nl (0..63), kq (0..7).
  const int nl = tid >> 3, kq = tid & 7;
  float4 rb[4];
#define LOADB(P)                                                             \
  do {                                                                       \
    const int hg_ = (P) / 12, rem_ = (P) % 12;                               \
    const int t_ = rem_ >> 2, per_ = rem_ & 3;                               \
    const float* bs_ = wq + (t_ * 512 + hg_ * 64 + nl) * 512 +               \
                       per_ * 128 + kq * 16;                                 \
    rb[0] = *(const float4*)(bs_);      rb[1] = *(const float4*)(bs_ + 4);   \
    rb[2] = *(const float4*)(bs_ + 8);  rb[3] = *(const float4*)(bs_ + 12);  \
  } while (0)
#define WRITEB(Bp)                                                           \
  do {                                                                       \
    *(f16x8*)((Bp) + nl * 128 + (((kq * 2)     ^ (nl & 7)) * 8)) =           \
        cvt8(rb[0], rb[1]);                                                  \
    *(f16x8*)((Bp) + nl * 128 + (((kq * 2 + 1) ^ (nl & 7)) * 8)) =           \
        cvt8(rb[2], rb[3]);                                                  \
  } while (0)

  f32x4 acc[2][4] = {};
  const float scale = 0.17677669529663687f;

  // prologue
  LOADB(0); SCHEDBAR(); VMCNT0(); WRITEB(B0); LOADB(1); SCHEDBAR();
  LGKM0(); BAR();

#pragma unroll 1
  for (int p = 0; p < 96; ++p) {
    f16* const Bc = (p & 1) ? B1 : B0;
    f16* const Bn = (p & 1) ? B0 : B1;

    // ---- 4 K32 substeps: 4 bf reads + 8 MFMA each ----
#pragma unroll
    for (int ks = 0; ks < 4; ++ks) {
      const int kst = (p & 3) * 4 + ks;
      f16x8 bf[4];
#pragma unroll
      for (int nt = 0; nt < 4; ++nt) {
        const int n = nt * 16 + jlo;
        bf[nt] = *(const f16x8*)(Bc + n * 128 + (((ks * 4 + g) ^ (n & 7)) * 8));
      }
      __builtin_amdgcn_s_setprio(1);
#pragma unroll
      for (int mt = 0; mt < 2; ++mt)
#pragma unroll
        for (int nt = 0; nt < 4; ++nt)
          acc[mt][nt] = MFMA16(af[mt][kst], bf[nt], acc[mt][nt]);
      __builtin_amdgcn_s_setprio(0);
    }
    if (p + 1 < 96) {
      VMCNT0();  // rb = period p+1 weights (issued at p-1)
      WRITEB(Bn);
      SCHEDBAR();
      if (p + 2 < 96) LOADB(p + 2);
      SCHEDBAR();
    }
    LGKM0();
    BAR();

    // ---- tile epilogue: acc -> LDS (q/k row-major, v transposed) ----
    if ((p & 3) == 3) {
      const int hg = p / 12, t = (p % 12) >> 2;
      float bias[4];
#pragma unroll
      for (int nt = 0; nt < 4; ++nt) bias[nt] = bq[t * 512 + hg * 64 + nt * 16 + jlo];
      if (t < 2) {
        f16* const dst = (t == 0) ? Q : Kl;
#pragma unroll
        for (int mt = 0; mt < 2; ++mt)
#pragma unroll
          for (int nt = 0; nt < 4; ++nt)
#pragma unroll
            for (int r = 0; r < 4; ++r)
              dst[(wave * 32 + mt * 16 + g * 4 + r) * 72 + nt * 16 + jlo] =
                  (f16)(acc[mt][nt][r] + bias[nt]);
      } else {
#pragma unroll
        for (int mt = 0; mt < 2; ++mt)
#pragma unroll
          for (int nt = 0; nt < 4; ++nt) {
            const int rowb = wave * 32 + mt * 16 + g * 4;
            const int win = rowb >> 6, s0 = rowb & 63;
            const int col = nt * 16 + jlo, hh = col >> 5, d = col & 31;
            f16x4 pk = { (f16)(acc[mt][nt][0] + bias[nt]), (f16)(acc[mt][nt][1] + bias[nt]),
                         (f16)(acc[mt][nt][2] + bias[nt]), (f16)(acc[mt][nt][3] + bias[nt]) };
            *(f16x4*)(V + ((win * 2 + hh) * 32 + d) * 72 + s0) = pk;
          }
      }
#pragma unroll
      for (int mt = 0; mt < 2; ++mt)
#pragma unroll
        for (int nt = 0; nt < 4; ++nt)
          acc[mt][nt] = (f32x4){0.f, 0.f, 0.f, 0.f};
    }

    // ---- attention for this head-group (after v epilogue) ----
    if (p % 12 == 11) {
      const int hg = p / 12;
      const int win = wave >> 1, hh = wave & 1, head = hg * 2 + hh;
      const int widx = (bm * 4 + win) & 63;
      const bool er = (widx >> 3) == 7;
      const bool ec = (widx & 7) == 7;
      f16* const Pw = (f16*)smem + wave * 4608;  // 9216B overlay of Q+K

      f16x8 qa[4], kb[4];
#pragma unroll
      for (int mt = 0; mt < 4; ++mt)
        qa[mt] = *(const f16x8*)(Q + (win * 64 + mt * 16 + jlo) * 72 + hh * 32 + g * 8);
#pragma unroll
      for (int nt = 0; nt < 4; ++nt)
        kb[nt] = *(const f16x8*)(Kl + (win * 64 + nt * 16 + jlo) * 72 + hh * 32 + g * 8);
      int gj[4];
#pragma unroll
      for (int nt = 0; nt < 4; ++nt) {
        int j = nt * 16 + jlo;
        gj[nt] = ((er && ((j >> 3) >= 4)) ? 2 : 0) | ((ec && ((j & 7) >= 4)) ? 1 : 0);
      }
      LGKM0();
      BAR();  // all waves done reading Q/K; V writes visible; Pw overlay safe

#pragma unroll
      for (int hf = 0; hf < 2; ++hf) {
        f32x4 sc[2][4] = {};
#pragma unroll
        for (int m2 = 0; m2 < 2; ++m2)
#pragma unroll
          for (int nt = 0; nt < 4; ++nt)
            sc[m2][nt] = MFMA16(qa[hf * 2 + m2], kb[nt], sc[m2][nt]);
        float rinv[2][4];
#pragma unroll
        for (int m2 = 0; m2 < 2; ++m2) {
#pragma unroll
          for (int r = 0; r < 4; ++r) {
            const int i = hf * 32 + m2 * 16 + g * 4 + r;
            const int gi = ((er && ((i >> 3) >= 4)) ? 2 : 0) | ((ec && ((i & 7) >= 4)) ? 1 : 0);
            float v0 = (gi == gj[0]) ? sc[m2][0][r] * scale : -1e9f;
            float v1 = (gi == gj[1]) ? sc[m2][1][r] * scale : -1e9f;
            float v2 = (gi == gj[2]) ? sc[m2][2][r] * scale : -1e9f;
            float v3 = (gi == gj[3]) ? sc[m2][3][r] * scale : -1e9f;
            float m = fmaxf(fmaxf(v0, v1), fmaxf(v2, v3));
            m = fmaxf(m, __shfl_xor(m, 1));
            m = fmaxf(m, __shfl_xor(m, 2));
            m = fmaxf(m, __shfl_xor(m, 4));
            m = fmaxf(m, __shfl_xor(m, 8));
            float p0 = __expf(v0 - m), p1 = __expf(v1 - m);
            float p2 = __expf(v2 - m), p3 = __expf(v3 - m);
            float s = p0 + p1 + p2 + p3;
            s += __shfl_xor(s, 1);
            s += __shfl_xor(s, 2);
            s += __shfl_xor(s, 4);
            s += __shfl_xor(s, 8);
            rinv[m2][r] = 1.0f / s;
            sc[m2][0][r] = p0; sc[m2][1][r] = p1; sc[m2][2][r] = p2; sc[m2][3][r] = p3;
          }
        }
#pragma unroll
        for (int m2 = 0; m2 < 2; ++m2)
#pragma unroll
          for (int nt = 0; nt < 4; ++nt)
#pragma unroll
            for (int r = 0; r < 4; ++r)
              Pw[(hf * 32 + m2 * 16 + g * 4 + r) * 72 + nt * 16 + jlo] =
                  (f16)sc[m2][nt][r];
        LGKM0();

        f32x4 o[2][2] = {};
#pragma unroll
        for (int ks = 0; ks < 2; ++ks) {
          f16x8 pa[2], vb[2];
#pragma unroll
          for (int m2 = 0; m2 < 2; ++m2)
            pa[m2] = *(const f16x8*)(Pw + (hf * 32 + m2 * 16 + jlo) * 72 + ks * 32 + g * 8);
#pragma unroll
          for (int nt = 0; nt < 2; ++nt)
            vb[nt] = *(const f16x8*)(V + ((win * 2 + hh) * 32 + nt * 16 + jlo) * 72 +
                                     ks * 32 + g * 8);
#pragma unroll
          for (int m2 = 0; m2 < 2; ++m2)
#pragma unroll
            for (int nt = 0; nt < 2; ++nt)
              o[m2][nt] = MFMA16(pa[m2], vb[nt], o[m2][nt]);
        }
        // stage normalized o into Pw stride-40 region (P rows of this half consumed)
#pragma unroll
        for (int m2 = 0; m2 < 2; ++m2)
#pragma unroll
          for (int nt = 0; nt < 2; ++nt)
#pragma unroll
            for (int r = 0; r < 4; ++r)
              Pw[(hf * 32 + m2 * 16 + g * 4 + r) * 40 + nt * 16 + jlo] =
                  (f16)(o[m2][nt][r] * rinv[m2][r]);
        LGKM0();
      }
      // write ao: 64 rows x 32 cols, one 64B chunk per lane-row
      f16* const arow = ao + (bm * 256 + win * 64 + lane) * 512 + head * 32;
#pragma unroll
      for (int c = 0; c < 4; ++c)
        *(f16x8*)(arow + c * 8) = *(const f16x8*)(Pw + lane * 40 + c * 8);
      LGKM0();
      BAR();  // attention reads/writes done before next hg overwrites Q/K/V/Pw
    }
  }
#undef LOADB
#undef WRITEB
}

// ---------------------------------------------------------------------------
// Kernel 2: output projection (R7-verified).  A(ao)-in-regs, 12->4 bn tiles,
// B reg-staged BK=32 dbuf, NT scatter via tok2patch.
// ---------------------------------------------------------------------------
__global__ __launch_bounds__(512, 2) void k_out(const f16* __restrict__ ao,
                                                const float* __restrict__ wo,
                                                const float* __restrict__ bo,
                                                float* __restrict__ out) {
  __shared__ __align__(16) char smem[86016];  // B0|B1 8KB + 8 x 8704B Cw (f32)
  f16* const B0 = (f16*)smem;
  f16* const B1 = (f16*)(smem + 8192);

  const int tid = threadIdx.x;
  const int lane = tid & 63, wave = tid >> 6;
  const int jlo = lane & 15, g = lane >> 4;
  const int bm = blockIdx.x;  // 256 blocks

  const int nl = tid >> 2, kq = tid & 3;
  const int bslot = (kq ^ ((nl >> 1) & 3)) * 8;

  const f16* const a0 = ao + (bm * 256 + wave * 32 + jlo) * 512 + g * 8;
  const f16* const a1 = a0 + 16 * 512;
  f16x8 af[2][16];
#pragma unroll
  for (int ks = 0; ks < 16; ++ks) {
    af[0][ks] = *(const f16x8*)(a0 + ks * 32);
    af[1][ks] = *(const f16x8*)(a1 + ks * 32);
  }

  f32x4 acc[2][8] = {};
  float4 rb[2];
#define LOADB(U2)                                                         \
  do {                                                                    \
    const int bn2_ = (U2) >> 4, k2_ = ((U2) & 15) * 32;                   \
    const float* bs_ = wo + (bn2_ * 128 + nl) * 512 + k2_ + kq * 8;       \
    rb[0] = *(const float4*)(bs_); rb[1] = *(const float4*)(bs_ + 4);     \
  } while (0)
#define WRITEB(Bp) do { *(f16x8*)((Bp) + nl * 32 + bslot) = cvt8(rb[0], rb[1]); } while (0)

  LOADB(0);
  SCHEDBAR();
  VMCNT0();
  WRITEB(B0);
  LOADB(1);
  LGKM0();
  BAR();

#pragma unroll 1
  for (int bn = 0; bn < 4; ++bn) {
    float* const Cw = (float*)(smem + 16384 + wave * 8704);
#pragma unroll
    for (int ks = 0; ks < 16; ++ks) {
      const int u = bn * 16 + ks;
      f16* const Bc = (u & 1) ? B1 : B0;
      f16* const Bn = (u & 1) ? B0 : B1;
      f16x8 bf[8];
#pragma unroll
      for (int nt = 0; nt < 8; ++nt) {
        const int n = nt * 16 + jlo;
        bf[nt] = *(const f16x8*)(Bc + n * 32 + ((g ^ ((n >> 1) & 3)) * 8));
      }
      __builtin_amdgcn_s_setprio(1);
#pragma unroll
      for (int mt = 0; mt < 2; ++mt)
#pragma unroll
        for (int nt = 0; nt < 8; ++nt)
          acc[mt][nt] = MFMA16(af[mt][ks], bf[nt], acc[mt][nt]);
      __builtin_amdgcn_s_setprio(0);
      VMCNT0();
      if (u + 1 < 64) WRITEB(Bn);
      SCHEDBAR();
      if (u + 2 < 64) LOADB(u + 2);
      LGKM0();
      BAR();
    }
#pragma unroll
    for (int hf = 0; hf < 2; ++hf) {
#pragma unroll
      for (int n2 = 0; n2 < 4; ++n2) {
        const int nt = hf * 4 + n2;
        const float bias = bo[bn * 128 + nt * 16 + jlo];
#pragma unroll
        for (int mt = 0; mt < 2; ++mt)
#pragma unroll
          for (int r = 0; r < 4; ++r)
            Cw[(mt * 16 + g * 4 + r) * 68 + n2 * 16 + jlo] = acc[mt][nt][r] + bias;
      }
      LGKM0();
#pragma unroll
      for (int q = 0; q < 8; ++q) {
        const int lr = (q >> 1) * 8 + (lane >> 3);
        const int ch = (q & 1) * 8 + (lane & 7);
        const int trow = bm * 256 + wave * 32 + lr;
        nts4f(*(const f32x4*)(Cw + lr * 68 + ch * 4),
              out + tok2patch(trow) + bn * 128 + hf * 64 + ch * 4);
      }
      LGKM0();
    }
#pragma unroll
    for (int mt = 0; mt < 2; ++mt)
#pragma unroll
      for (int nt = 0; nt < 8; ++nt)
        acc[mt][nt] = (f32x4){0.f, 0.f, 0.f, 0.f};
  }
#undef LOADB
#undef WRITEB
}

extern "C" void kernel_launch(void* const* d_in, const int* in_sizes, int n_in,
                              void* d_out, int out_size, void* d_ws, size_t ws_size,
                              hipStream_t stream) {
  const float* x  = (const float*)d_in[0];
  const float* wq = (const float*)d_in[1];
  const float* bq = (const float*)d_in[2];
  const float* wo = (const float*)d_in[3];
  const float* bo = (const float*)d_in[4];
  float* out = (float*)d_out;

  f16* ao = (f16*)d_ws;  // attention output (64 MiB)

  k_fused<<<dim3(256), 512, 0, stream>>>(x, wq, bq, ao);
  k_out<<<dim3(256), 512, 0, stream>>>(ao, wo, bo, out);
}